// Round 8
// baseline (5172.094 us; speedup 1.0000x reference)
//
#include <hip/hip_runtime.h>

// ---------------------------------------------------------------------------
// peepLSTM (B=512,S=256,H=768,E=6,C=10,V=3) — fp16 split MFMA
// r8 = r7 (producer-consumer wave specialization) + CRITICAL FIX:
//   all LDS counter atomics (chunkDone / ldsRdy / zdone) are now lane-0
//   guarded (+1 per WAVE as the targets assume, not +1 per LANE).
//   Wave-level lgkmcnt drain on the release atomic orders the whole wave's
//   LDS accesses, so a single lane's bump is sufficient and correct.
// ---------------------------------------------------------------------------

typedef _Float16 f16x8 __attribute__((ext_vector_type(8)));
typedef _Float16 f16x4 __attribute__((ext_vector_type(4)));
typedef float    f32x4 __attribute__((ext_vector_type(4)));
typedef unsigned long long u64;

#define Hdim  768
#define Bdim  512
#define Sdim  256
#define NSTEP 255
#define Edim  6
#define NCls  10
#define NGRP  16
#define NRB   12
#define GC    32
#define HB    64
#define NKK   24
#define NCH   12            // 64-k chunks
#define CSTR  776
#define XSTR  260
#define PLANE (Bdim * Hdim)
#define SCL      4096.0f
#define SCL_INV  2.44140625e-4f

#define WP_FRAGS   (2 * NRB * 4 * NKK * 64)
#define WS_CBUF    0u
#define WS_HFIN    (2u * 2u * PLANE * 2u)
#define WS_BAR     (WS_HFIN + Bdim * Hdim * 4u)
#define WS_WPK     (WS_BAR + 4096u)
#define WS_BAR_BYTES (NGRP * 16u * 4u)

__device__ __forceinline__ float sigf(float z) { return 1.0f / (1.0f + __expf(-z)); }

__device__ __forceinline__ f32x4 mf(f16x8 a, f16x8 b, f32x4 c) {
    return __builtin_amdgcn_mfma_f32_16x16x32_f16(a, b, c, 0, 0, 0);
}

__device__ __forceinline__ void keepalive(f16x8& x) {
    asm volatile("" : "+v"(x));
}

// ---------------- prep: split W into fp16 hi / (lo*4096) fragment planes ----
__global__ void __launch_bounds__(256)
prep_w(const float* __restrict__ Wfh, const float* __restrict__ Wih,
       _Float16* __restrict__ wpk)
{
    const int fid  = blockIdx.x * 256 + threadIdx.x;
    const int lane = fid & 63;
    const int t1   = fid >> 6;
    const int kk   = t1 % NKK;
    const int gi   = t1 / NKK;            // (gate*12+rb)*4+sub
    const int sub  = gi & 3;
    const int t3   = gi >> 2;
    const int rb   = t3 % NRB;
    const int gate = t3 / NRB;
    const int q = lane >> 4, r = lane & 15;
    const int row = rb * 64 + sub * 16 + r;
    const int col = kk * 32 + q * 8;
    const float* src = (gate ? Wih : Wfh) + (size_t)row * Hdim + col;
    f16x8 hi, lo;
    #pragma unroll
    for (int j = 0; j < 8; ++j) {
        const float v = src[j];
        const _Float16 h = (_Float16)v;
        hi[j] = h;
        lo[j] = (_Float16)((v - (float)h) * SCL);
    }
    *(f16x8*)&wpk[(size_t)fid * 8] = hi;
    *(f16x8*)&wpk[((size_t)WP_FRAGS + fid) * 8] = lo;
}

// ---------------- main persistent kernel ------------------------------------
__global__ void __launch_bounds__(768, 1)
lstm_persist(const int* __restrict__ xk, const float* __restrict__ emb,
             const float* __restrict__ Wfx, const float* __restrict__ bfv,
             const float* __restrict__ Wix, const float* __restrict__ biv,
             const float* __restrict__ Wox, const float* __restrict__ Woh,
             const float* __restrict__ bov,
             const float* __restrict__ Wcx, const float* __restrict__ bcv,
             const float* __restrict__ cinit,
             const _Float16* __restrict__ wpk,
             _Float16* __restrict__ cbuf, float* __restrict__ hfin,
             unsigned int* __restrict__ bar)
{
    __shared__ __align__(16) _Float16 ldsH[GC * CSTR];        // 49,664 B
    __shared__ __align__(16) _Float16 ldsM[GC * CSTR];        // 49,664 B
    __shared__ __align__(16) float    tbl[3 * HB * 4];        //  3,072 B
    __shared__ __align__(16) float    zbuf[2][HB * GC];       // 16,384 B
    __shared__ __align__(4)  unsigned char xtok[GC * XSTR];   //  8,320 B
    __shared__ unsigned int ldsRdy[NCH];                      // +4 / step
    __shared__ unsigned int chunkDone[NCH];                   // +8 / step
    __shared__ unsigned int zdone, fdone;
    __shared__ int s_flag;

    const int tid  = threadIdx.x;
    const int w    = tid >> 6;
    const int lane = tid & 63;
    const int q    = lane >> 4;
    const int r    = lane & 15;
    const int bid  = blockIdx.x;
    const int g    = bid & 15;
    const int rb   = bid >> 4;
    const int blkh0 = rb * HB;
    const int gc0   = g * GC;

    if (tid == 0) {
        s_flag = 0; zdone = 0u; fdone = 0u;
        #pragma unroll
        for (int j = 0; j < NCH; ++j) { ldsRdy[j] = 0u; chunkDone[j] = 0u; }
    }
    __syncthreads();
    if (tid < 256) {
        if (xk[(size_t)gc0 * Sdim + 2 * tid + 1] != 0) s_flag = 1;
    }
    if (tid < 3 * HB) {
        const int v  = tid >> 6;
        const int hl = tid & 63;
        const int hg = blkh0 + hl;
        float pf = bfv[hg], pi = biv[hg], po = bov[hg], pc = bcv[hg];
        #pragma unroll
        for (int e = 0; e < Edim; ++e) {
            const float ev = emb[v * Edim + e];
            pf += Wfx[hg * Edim + e] * ev;
            pi += Wix[hg * Edim + e] * ev;
            po += Wox[hg * Edim + e] * ev;
            pc += Wcx[hg * Edim + e] * ev;
        }
        float* t = &tbl[(v * HB + hl) * 4];
        t[0] = pf; t[1] = pi; t[2] = po; t[3] = sigf(pc);
    }
    __syncthreads();
    const int is64 = (s_flag == 0);

    if (tid < 512) {   // tokens -> LDS bytes
        const int col   = tid >> 4;
        const int sbase = (tid & 15) * 16;
        const size_t rowb = (size_t)(gc0 + col) * Sdim;
        for (int k2 = 0; k2 < 16; ++k2) {
            const int s0 = sbase + k2;
            const size_t idx = rowb + s0;
            xtok[col * XSTR + s0] = (unsigned char)xk[is64 ? (idx << 1) : idx];
        }
    }

    // step-0 LDS tiles from c_init (all 768 threads, 32 iters)
    for (int i = 0; i < 32; ++i) {
        const int idx = tid + i * 768;
        const int col = idx & 31, k = idx >> 5;
        const float v = cinit[(size_t)k * Bdim + gc0 + col];
        const _Float16 h = (_Float16)v;
        ldsH[col * CSTR + k] = h;
        ldsM[col * CSTR + k] = (_Float16)((v - (float)h) * SCL);
    }
    __syncthreads();     // init done; from here on, LDS-counter dataflow only

    if (w < 8) {
        // =================== consumer (MFMA) waves =========================
        const int gt  = w >> 2;          // 0 = f, 1 = i
        const int sub = w & 3;
        const int hq0 = blkh0 + sub * 16 + q * 4;
        const int gi  = (gt * NRB + rb) * 4 + sub;

        f16x8 whi[NKK], wlo[NKK];
        #pragma unroll
        for (int kk = 0; kk < NKK; ++kk) {
            whi[kk] = *(const f16x8*)&wpk[((size_t)(gi * NKK + kk) * 64 + lane) * 8];
            wlo[kk] = *(const f16x8*)&wpk[((size_t)WP_FRAGS + (size_t)(gi * NKK + kk) * 64 + lane) * 8];
        }
        #pragma unroll
        for (int kk = 0; kk < NKK; ++kk) { keepalive(whi[kk]); keepalive(wlo[kk]); }

        float cst[2][4];
        #pragma unroll
        for (int ct = 0; ct < 2; ++ct) {
            const int b = gc0 + ct * 16 + r;
            #pragma unroll
            for (int reg = 0; reg < 4; ++reg)
                cst[ct][reg] = cinit[(size_t)(hq0 + reg) * Bdim + b];
        }

        for (int s = 0; s < NSTEP; ++s) {
            f32x4 a0h = {0,0,0,0}, a0x = {0,0,0,0}, a1h = {0,0,0,0}, a1x = {0,0,0,0};
            const unsigned rdyTgt = 4u * (unsigned)s;
            for (int j = 0; j < NCH; ++j) {
                while (__hip_atomic_load(&ldsRdy[j], __ATOMIC_ACQUIRE,
                                         __HIP_MEMORY_SCOPE_WORKGROUP) < rdyTgt)
                    __builtin_amdgcn_s_sleep(1);
                #pragma unroll
                for (int k2 = 0; k2 < 2; ++k2) {
                    const int kk = j * 2 + k2;
                    const int lo = kk * 32 + q * 8;
                    const f16x8 bh0 = *(const f16x8*)&ldsH[ r       * CSTR + lo];
                    const f16x8 bm0 = *(const f16x8*)&ldsM[ r       * CSTR + lo];
                    const f16x8 bh1 = *(const f16x8*)&ldsH[(16 + r) * CSTR + lo];
                    const f16x8 bm1 = *(const f16x8*)&ldsM[(16 + r) * CSTR + lo];
                    a0h = mf(whi[kk], bh0, a0h);
                    a0x = mf(whi[kk], bm0, a0x);
                    a0x = mf(wlo[kk], bh0, a0x);
                    a1h = mf(whi[kk], bh1, a1h);
                    a1x = mf(whi[kk], bm1, a1x);
                    a1x = mf(wlo[kk], bh1, a1x);
                }
                if (lane == 0)                      // FIX: +1 per wave
                    __hip_atomic_fetch_add(&chunkDone[j], 1u, __ATOMIC_RELEASE,
                                           __HIP_MEMORY_SCOPE_WORKGROUP);
            }

            if (gt) {
                // i-waves: export z_i into parity buffer, bump zdone
                float* zp = zbuf[s & 1];
                #pragma unroll
                for (int ct = 0; ct < 2; ++ct) {
                    const f32x4 zh = ct ? a1h : a0h;
                    const f32x4 zx = ct ? a1x : a0x;
                    #pragma unroll
                    for (int reg = 0; reg < 4; ++reg)
                        zp[(sub * 16 + q * 4 + reg) * GC + ct * 16 + r] =
                            zh[reg] + zx[reg] * SCL_INV;
                }
                if (lane == 0)                      // FIX: +1 per wave
                    __hip_atomic_fetch_add(&zdone, 1u, __ATOMIC_RELEASE,
                                           __HIP_MEMORY_SCOPE_WORKGROUP);
            } else {
                // f-waves: wait z_i, epilogue
                const unsigned zTgt = 4u * (unsigned)(s + 1);
                while (__hip_atomic_load(&zdone, __ATOMIC_ACQUIRE,
                                         __HIP_MEMORY_SCOPE_WORKGROUP) < zTgt)
                    __builtin_amdgcn_s_sleep(1);
                const float* zp = zbuf[s & 1];

                if (s != NSTEP - 1) {
                    _Float16* cwH = cbuf + (size_t)(((s + 1) & 1) * 2) * PLANE;
                    _Float16* cwM = cwH + PLANE;
                    #pragma unroll
                    for (int ct = 0; ct < 2; ++ct) {
                        const int bl = ct * 16 + r;
                        const int v  = xtok[bl * XSTR + s];
                        const float* tb = &tbl[(v * HB + sub * 16 + q * 4) * 4];
                        const f32x4 zh = ct ? a1h : a0h;
                        const f32x4 zx = ct ? a1x : a0x;
                        f16x4 cvh, cvm;
                        #pragma unroll
                        for (int reg = 0; reg < 4; ++reg) {
                            const float zf = zh[reg] + zx[reg] * SCL_INV;
                            const float zi = zp[(sub * 16 + q * 4 + reg) * GC + bl];
                            const float* tt = tb + reg * 4;
                            const float fg = sigf(zf + tt[0]);
                            const float ig = sigf(zi + tt[1]);
                            const float cn = tt[3] * ig + cst[ct][reg] * fg;
                            cst[ct][reg] = cn;
                            const _Float16 ch = (_Float16)cn;
                            cvh[reg] = ch;
                            cvm[reg] = (_Float16)((cn - (float)ch) * SCL);
                        }
                        u64 uh, um;
                        __builtin_memcpy(&uh, &cvh, 8);
                        __builtin_memcpy(&um, &cvm, 8);
                        const size_t eo = (size_t)(gc0 + bl) * Hdim + hq0;
                        __hip_atomic_store((u64*)&cwH[eo], uh,
                                           __ATOMIC_RELAXED, __HIP_MEMORY_SCOPE_AGENT);
                        __hip_atomic_store((u64*)&cwM[eo], um,
                                           __ATOMIC_RELAXED, __HIP_MEMORY_SCOPE_AGENT);
                    }
                    // drain own stores; 4th f-wave fires the producer flag
                    asm volatile("s_waitcnt vmcnt(0)" ::: "memory");
                    if (lane == 0) {
                        const unsigned old = __hip_atomic_fetch_add(&fdone, 1u,
                                             __ATOMIC_ACQ_REL, __HIP_MEMORY_SCOPE_WORKGROUP);
                        if (old == 4u * (unsigned)s + 3u)
                            __hip_atomic_store(&bar[g * 16 + rb], (unsigned)(s + 1),
                                               __ATOMIC_RELAXED, __HIP_MEMORY_SCOPE_AGENT);
                    }
                } else {
                    // last step: o-gate (full-K over resident tile), h = tanh(c)*o
                    f32x4 o0h = {0,0,0,0}, o0x = {0,0,0,0}, o1h = {0,0,0,0}, o1x = {0,0,0,0};
                    const int arow = blkh0 + sub * 16 + r;
                    #pragma unroll
                    for (int kk = 0; kk < NKK; ++kk) {
                        const float* wp = Woh + (size_t)arow * Hdim + kk * 32 + q * 8;
                        f16x8 who;
                        #pragma unroll
                        for (int jj = 0; jj < 8; ++jj) who[jj] = (_Float16)wp[jj];
                        const int lo = kk * 32 + q * 8;
                        const f16x8 bh0 = *(const f16x8*)&ldsH[ r       * CSTR + lo];
                        const f16x8 bm0 = *(const f16x8*)&ldsM[ r       * CSTR + lo];
                        const f16x8 bh1 = *(const f16x8*)&ldsH[(16 + r) * CSTR + lo];
                        const f16x8 bm1 = *(const f16x8*)&ldsM[(16 + r) * CSTR + lo];
                        o0h = mf(who, bh0, o0h);  o0x = mf(who, bm0, o0x);
                        o1h = mf(who, bh1, o1h);  o1x = mf(who, bm1, o1x);
                    }
                    #pragma unroll
                    for (int ct = 0; ct < 2; ++ct) {
                        const int bl = ct * 16 + r;
                        const int v  = xtok[bl * XSTR + s];
                        const float* tb = &tbl[(v * HB + sub * 16 + q * 4) * 4];
                        const f32x4 zh = ct ? a1h : a0h;
                        const f32x4 zx = ct ? a1x : a0x;
                        const f32x4 zoh = ct ? o1h : o0h;
                        const f32x4 zox = ct ? o1x : o0x;
                        f32x4 hv;
                        #pragma unroll
                        for (int reg = 0; reg < 4; ++reg) {
                            const float zf = zh[reg] + zx[reg] * SCL_INV;
                            const float zi = zp[(sub * 16 + q * 4 + reg) * GC + bl];
                            const float zo = zoh[reg] + zox[reg] * SCL_INV;
                            const float* tt = tb + reg * 4;
                            const float fg = sigf(zf + tt[0]);
                            const float ig = sigf(zi + tt[1]);
                            const float og = sigf(zo + tt[2]);
                            const float cn = tt[3] * ig + cst[ct][reg] * fg;
                            const float e  = __expf(-2.0f * fabsf(cn));
                            const float th = __builtin_copysignf((1.0f - e) / (1.0f + e), cn);
                            hv[reg] = th * og;
                        }
                        *(f32x4*)&hfin[(size_t)(gc0 + bl) * Hdim + hq0] = hv;
                    }
                }
            }
        }
    } else {
        // =================== staging waves (w = 8..11) =====================
        // 4 waves x 64 lanes = 256 slots; per chunk: 2 planes x 32 cols x 64 k
        // slot -> plane p, col, 16-k segment; 4 x 8B per lane per chunk.
        const int sw   = w - 8;
        const int slot = sw * 64 + lane;      // 0..255
        const int p    = slot >> 7;           // plane 0=H 1=M
        const int colq = (slot >> 2) & 31;    // col
        const int seg  = slot & 3;            // 16-k segment
        _Float16* ldsP = p ? ldsM : ldsH;
        const size_t rowo = (size_t)(gc0 + colq) * Hdim;

        for (int s = 1; s < NSTEP; ++s) {
            const _Float16* cr = cbuf + (size_t)((s & 1) * 2 + p) * PLANE + rowo;
            u64 d[NCH][4];
            #pragma unroll
            for (int j = 0; j < NCH; ++j) {
                while (__hip_atomic_load(&bar[g * 16 + j], __ATOMIC_RELAXED,
                                         __HIP_MEMORY_SCOPE_AGENT) < (unsigned)s)
                    __builtin_amdgcn_s_sleep(2);
                const size_t ko = (size_t)j * 64 + seg * 16;
                #pragma unroll
                for (int t = 0; t < 4; ++t)
                    d[j][t] = __hip_atomic_load((const u64*)&cr[ko + 4 * t],
                                                __ATOMIC_RELAXED, __HIP_MEMORY_SCOPE_AGENT);
            }
            const unsigned doneTgt = 8u * (unsigned)s;
            #pragma unroll
            for (int j = 0; j < NCH; ++j) {
                while (__hip_atomic_load(&chunkDone[j], __ATOMIC_ACQUIRE,
                                         __HIP_MEMORY_SCOPE_WORKGROUP) < doneTgt)
                    __builtin_amdgcn_s_sleep(1);
                u64* dst = (u64*)&ldsP[colq * CSTR + j * 64 + seg * 16];
                dst[0] = d[j][0]; dst[1] = d[j][1]; dst[2] = d[j][2]; dst[3] = d[j][3];
                if (lane == 0)                      // FIX: +1 per wave
                    __hip_atomic_fetch_add(&ldsRdy[j], 1u, __ATOMIC_RELEASE,
                                           __HIP_MEMORY_SCOPE_WORKGROUP);
            }
        }
    }
}

__global__ void __launch_bounds__(64)
proj_kernel(const float* __restrict__ hfin, const float* __restrict__ Wph,
            const float* __restrict__ bpv, float* __restrict__ out)
{
    const int b = blockIdx.x;
    const int lane = threadIdx.x;
    float acc[NCls];
    #pragma unroll
    for (int c = 0; c < NCls; ++c) acc[c] = 0.f;
    const float* hb = &hfin[(size_t)b * Hdim];
    for (int i = 0; i < Hdim / 64; ++i) {
        const float hv = hb[lane + i * 64];
        #pragma unroll
        for (int c = 0; c < NCls; ++c)
            acc[c] += Wph[c * Hdim + lane + i * 64] * hv;
    }
    #pragma unroll
    for (int c = 0; c < NCls; ++c) {
        float v = acc[c];
        #pragma unroll
        for (int off = 32; off > 0; off >>= 1)
            v += __shfl_xor(v, off, 64);
        acc[c] = v + bpv[c];
    }
    float m = acc[0];
    #pragma unroll
    for (int c = 1; c < NCls; ++c) m = fmaxf(m, acc[c]);
    float ssum = 0.f;
    #pragma unroll
    for (int c = 0; c < NCls; ++c) ssum += __expf(acc[c] - m);
    const float lse = m + __logf(ssum);
    if (lane < NCls) out[b * NCls + lane] = acc[lane] - lse;
}

extern "C" void kernel_launch(void* const* d_in, const int* in_sizes, int n_in,
                              void* d_out, int out_size, void* d_ws, size_t ws_size,
                              hipStream_t stream)
{
    const int*   xk    = (const int*)d_in[0];
    const float* emb   = (const float*)d_in[1];
    const float* Wfx   = (const float*)d_in[2];
    const float* Wfh   = (const float*)d_in[3];
    const float* bfv   = (const float*)d_in[4];
    const float* Wix   = (const float*)d_in[5];
    const float* Wih   = (const float*)d_in[6];
    const float* biv   = (const float*)d_in[7];
    const float* Wox   = (const float*)d_in[8];
    const float* Woh   = (const float*)d_in[9];
    const float* bov   = (const float*)d_in[10];
    const float* Wcx   = (const float*)d_in[11];
    const float* bcv   = (const float*)d_in[12];
    const float* Wph   = (const float*)d_in[13];
    const float* bpv   = (const float*)d_in[14];
    const float* cinit = (const float*)d_in[15];

    char* ws = (char*)d_ws;
    _Float16*     cbuf = (_Float16*)(ws + WS_CBUF);
    float*        hfin = (float*)(ws + WS_HFIN);
    unsigned int* bar  = (unsigned int*)(ws + WS_BAR);
    _Float16*     wpk  = (_Float16*)(ws + WS_WPK);

    hipMemsetAsync(bar, 0, WS_BAR_BYTES, stream);

    prep_w<<<dim3(WP_FRAGS / 256), dim3(256), 0, stream>>>(Wfh, Wih, wpk);

    lstm_persist<<<dim3(NGRP * NRB), dim3(768), 0, stream>>>(
        xk, emb, Wfx, bfv, Wix, biv, Wox, Woh, bov, Wcx, bcv,
        cinit, wpk, cbuf, hfin, bar);

    proj_kernel<<<dim3(Bdim), dim3(64), 0, stream>>>(hfin, Wph, bpv, (float*)d_out);
}

// Round 9
// 4713.458 us; speedup vs baseline: 1.0973x; 1.0973x over previous
//
#include <hip/hip_runtime.h>

// ---------------------------------------------------------------------------
// peepLSTM (B=512,S=256,H=768,E=6,C=10,V=3) — fp16 split MFMA
// r9 = r8 (producer-consumer wave specialization, lane-0 counters) + fixes:
//   * staging loop is depth-2 software-pipelined, ONE chunk resident + ONE
//     prefetch (8 u64 regs) — r8's u64 d[12][4] spilled to scratch (VGPR=84,
//     FETCH 6.7GB). No bulk buffer -> no spill.
//   * bar flag polls sleep(4) to cut poll pressure; LDS polls stay sleep(1).
// ---------------------------------------------------------------------------

typedef _Float16 f16x8 __attribute__((ext_vector_type(8)));
typedef _Float16 f16x4 __attribute__((ext_vector_type(4)));
typedef float    f32x4 __attribute__((ext_vector_type(4)));
typedef unsigned long long u64;

#define Hdim  768
#define Bdim  512
#define Sdim  256
#define NSTEP 255
#define Edim  6
#define NCls  10
#define NGRP  16
#define NRB   12
#define GC    32
#define HB    64
#define NKK   24
#define NCH   12            // 64-k chunks
#define CSTR  776
#define XSTR  260
#define PLANE (Bdim * Hdim)
#define SCL      4096.0f
#define SCL_INV  2.44140625e-4f

#define WP_FRAGS   (2 * NRB * 4 * NKK * 64)
#define WS_CBUF    0u
#define WS_HFIN    (2u * 2u * PLANE * 2u)
#define WS_BAR     (WS_HFIN + Bdim * Hdim * 4u)
#define WS_WPK     (WS_BAR + 4096u)
#define WS_BAR_BYTES (NGRP * 16u * 4u)

__device__ __forceinline__ float sigf(float z) { return 1.0f / (1.0f + __expf(-z)); }

__device__ __forceinline__ f32x4 mf(f16x8 a, f16x8 b, f32x4 c) {
    return __builtin_amdgcn_mfma_f32_16x16x32_f16(a, b, c, 0, 0, 0);
}

__device__ __forceinline__ void keepalive(f16x8& x) {
    asm volatile("" : "+v"(x));
}

// ---------------- prep: split W into fp16 hi / (lo*4096) fragment planes ----
__global__ void __launch_bounds__(256)
prep_w(const float* __restrict__ Wfh, const float* __restrict__ Wih,
       _Float16* __restrict__ wpk)
{
    const int fid  = blockIdx.x * 256 + threadIdx.x;
    const int lane = fid & 63;
    const int t1   = fid >> 6;
    const int kk   = t1 % NKK;
    const int gi   = t1 / NKK;            // (gate*12+rb)*4+sub
    const int sub  = gi & 3;
    const int t3   = gi >> 2;
    const int rb   = t3 % NRB;
    const int gate = t3 / NRB;
    const int q = lane >> 4, r = lane & 15;
    const int row = rb * 64 + sub * 16 + r;
    const int col = kk * 32 + q * 8;
    const float* src = (gate ? Wih : Wfh) + (size_t)row * Hdim + col;
    f16x8 hi, lo;
    #pragma unroll
    for (int j = 0; j < 8; ++j) {
        const float v = src[j];
        const _Float16 h = (_Float16)v;
        hi[j] = h;
        lo[j] = (_Float16)((v - (float)h) * SCL);
    }
    *(f16x8*)&wpk[(size_t)fid * 8] = hi;
    *(f16x8*)&wpk[((size_t)WP_FRAGS + fid) * 8] = lo;
}

// ---------------- main persistent kernel ------------------------------------
__global__ void __launch_bounds__(768, 1)
lstm_persist(const int* __restrict__ xk, const float* __restrict__ emb,
             const float* __restrict__ Wfx, const float* __restrict__ bfv,
             const float* __restrict__ Wix, const float* __restrict__ biv,
             const float* __restrict__ Wox, const float* __restrict__ Woh,
             const float* __restrict__ bov,
             const float* __restrict__ Wcx, const float* __restrict__ bcv,
             const float* __restrict__ cinit,
             const _Float16* __restrict__ wpk,
             _Float16* __restrict__ cbuf, float* __restrict__ hfin,
             unsigned int* __restrict__ bar)
{
    __shared__ __align__(16) _Float16 ldsH[GC * CSTR];        // 49,664 B
    __shared__ __align__(16) _Float16 ldsM[GC * CSTR];        // 49,664 B
    __shared__ __align__(16) float    tbl[3 * HB * 4];        //  3,072 B
    __shared__ __align__(16) float    zbuf[2][HB * GC];       // 16,384 B
    __shared__ __align__(4)  unsigned char xtok[GC * XSTR];   //  8,320 B
    __shared__ unsigned int ldsRdy[NCH];                      // +4 / step
    __shared__ unsigned int chunkDone[NCH];                   // +8 / step
    __shared__ unsigned int zdone, fdone;
    __shared__ int s_flag;

    const int tid  = threadIdx.x;
    const int w    = tid >> 6;
    const int lane = tid & 63;
    const int q    = lane >> 4;
    const int r    = lane & 15;
    const int bid  = blockIdx.x;
    const int g    = bid & 15;
    const int rb   = bid >> 4;
    const int blkh0 = rb * HB;
    const int gc0   = g * GC;

    if (tid == 0) {
        s_flag = 0; zdone = 0u; fdone = 0u;
        #pragma unroll
        for (int j = 0; j < NCH; ++j) { ldsRdy[j] = 0u; chunkDone[j] = 0u; }
    }
    __syncthreads();
    if (tid < 256) {
        if (xk[(size_t)gc0 * Sdim + 2 * tid + 1] != 0) s_flag = 1;
    }
    if (tid < 3 * HB) {
        const int v  = tid >> 6;
        const int hl = tid & 63;
        const int hg = blkh0 + hl;
        float pf = bfv[hg], pi = biv[hg], po = bov[hg], pc = bcv[hg];
        #pragma unroll
        for (int e = 0; e < Edim; ++e) {
            const float ev = emb[v * Edim + e];
            pf += Wfx[hg * Edim + e] * ev;
            pi += Wix[hg * Edim + e] * ev;
            po += Wox[hg * Edim + e] * ev;
            pc += Wcx[hg * Edim + e] * ev;
        }
        float* t = &tbl[(v * HB + hl) * 4];
        t[0] = pf; t[1] = pi; t[2] = po; t[3] = sigf(pc);
    }
    __syncthreads();
    const int is64 = (s_flag == 0);

    if (tid < 512) {   // tokens -> LDS bytes
        const int col   = tid >> 4;
        const int sbase = (tid & 15) * 16;
        const size_t rowb = (size_t)(gc0 + col) * Sdim;
        for (int k2 = 0; k2 < 16; ++k2) {
            const int s0 = sbase + k2;
            const size_t idx = rowb + s0;
            xtok[col * XSTR + s0] = (unsigned char)xk[is64 ? (idx << 1) : idx];
        }
    }

    // step-0 LDS tiles from c_init (all 768 threads, 32 iters)
    for (int i = 0; i < 32; ++i) {
        const int idx = tid + i * 768;
        const int col = idx & 31, k = idx >> 5;
        const float v = cinit[(size_t)k * Bdim + gc0 + col];
        const _Float16 h = (_Float16)v;
        ldsH[col * CSTR + k] = h;
        ldsM[col * CSTR + k] = (_Float16)((v - (float)h) * SCL);
    }
    __syncthreads();     // init done; from here on, LDS-counter dataflow only

    if (w < 8) {
        // =================== consumer (MFMA) waves =========================
        const int gt  = w >> 2;          // 0 = f, 1 = i
        const int sub = w & 3;
        const int hq0 = blkh0 + sub * 16 + q * 4;
        const int gi  = (gt * NRB + rb) * 4 + sub;

        f16x8 whi[NKK], wlo[NKK];
        #pragma unroll
        for (int kk = 0; kk < NKK; ++kk) {
            whi[kk] = *(const f16x8*)&wpk[((size_t)(gi * NKK + kk) * 64 + lane) * 8];
            wlo[kk] = *(const f16x8*)&wpk[((size_t)WP_FRAGS + (size_t)(gi * NKK + kk) * 64 + lane) * 8];
        }
        #pragma unroll
        for (int kk = 0; kk < NKK; ++kk) { keepalive(whi[kk]); keepalive(wlo[kk]); }

        float cst[2][4];
        #pragma unroll
        for (int ct = 0; ct < 2; ++ct) {
            const int b = gc0 + ct * 16 + r;
            #pragma unroll
            for (int reg = 0; reg < 4; ++reg)
                cst[ct][reg] = cinit[(size_t)(hq0 + reg) * Bdim + b];
        }

        for (int s = 0; s < NSTEP; ++s) {
            f32x4 a0h = {0,0,0,0}, a0x = {0,0,0,0}, a1h = {0,0,0,0}, a1x = {0,0,0,0};
            const unsigned rdyTgt = 4u * (unsigned)s;
            for (int j = 0; j < NCH; ++j) {
                while (__hip_atomic_load(&ldsRdy[j], __ATOMIC_ACQUIRE,
                                         __HIP_MEMORY_SCOPE_WORKGROUP) < rdyTgt)
                    __builtin_amdgcn_s_sleep(1);
                #pragma unroll
                for (int k2 = 0; k2 < 2; ++k2) {
                    const int kk = j * 2 + k2;
                    const int lo = kk * 32 + q * 8;
                    const f16x8 bh0 = *(const f16x8*)&ldsH[ r       * CSTR + lo];
                    const f16x8 bm0 = *(const f16x8*)&ldsM[ r       * CSTR + lo];
                    const f16x8 bh1 = *(const f16x8*)&ldsH[(16 + r) * CSTR + lo];
                    const f16x8 bm1 = *(const f16x8*)&ldsM[(16 + r) * CSTR + lo];
                    a0h = mf(whi[kk], bh0, a0h);
                    a0x = mf(whi[kk], bm0, a0x);
                    a0x = mf(wlo[kk], bh0, a0x);
                    a1h = mf(whi[kk], bh1, a1h);
                    a1x = mf(whi[kk], bm1, a1x);
                    a1x = mf(wlo[kk], bh1, a1x);
                }
                if (lane == 0)
                    __hip_atomic_fetch_add(&chunkDone[j], 1u, __ATOMIC_RELEASE,
                                           __HIP_MEMORY_SCOPE_WORKGROUP);
            }

            if (gt) {
                // i-waves: export z_i into parity buffer, bump zdone
                float* zp = zbuf[s & 1];
                #pragma unroll
                for (int ct = 0; ct < 2; ++ct) {
                    const f32x4 zh = ct ? a1h : a0h;
                    const f32x4 zx = ct ? a1x : a0x;
                    #pragma unroll
                    for (int reg = 0; reg < 4; ++reg)
                        zp[(sub * 16 + q * 4 + reg) * GC + ct * 16 + r] =
                            zh[reg] + zx[reg] * SCL_INV;
                }
                if (lane == 0)
                    __hip_atomic_fetch_add(&zdone, 1u, __ATOMIC_RELEASE,
                                           __HIP_MEMORY_SCOPE_WORKGROUP);
            } else {
                // f-waves: wait z_i, epilogue
                const unsigned zTgt = 4u * (unsigned)(s + 1);
                while (__hip_atomic_load(&zdone, __ATOMIC_ACQUIRE,
                                         __HIP_MEMORY_SCOPE_WORKGROUP) < zTgt)
                    __builtin_amdgcn_s_sleep(1);
                const float* zp = zbuf[s & 1];

                if (s != NSTEP - 1) {
                    _Float16* cwH = cbuf + (size_t)(((s + 1) & 1) * 2) * PLANE;
                    _Float16* cwM = cwH + PLANE;
                    #pragma unroll
                    for (int ct = 0; ct < 2; ++ct) {
                        const int bl = ct * 16 + r;
                        const int v  = xtok[bl * XSTR + s];
                        const float* tb = &tbl[(v * HB + sub * 16 + q * 4) * 4];
                        const f32x4 zh = ct ? a1h : a0h;
                        const f32x4 zx = ct ? a1x : a0x;
                        f16x4 cvh, cvm;
                        #pragma unroll
                        for (int reg = 0; reg < 4; ++reg) {
                            const float zf = zh[reg] + zx[reg] * SCL_INV;
                            const float zi = zp[(sub * 16 + q * 4 + reg) * GC + bl];
                            const float* tt = tb + reg * 4;
                            const float fg = sigf(zf + tt[0]);
                            const float ig = sigf(zi + tt[1]);
                            const float cn = tt[3] * ig + cst[ct][reg] * fg;
                            cst[ct][reg] = cn;
                            const _Float16 ch = (_Float16)cn;
                            cvh[reg] = ch;
                            cvm[reg] = (_Float16)((cn - (float)ch) * SCL);
                        }
                        u64 uh, um;
                        __builtin_memcpy(&uh, &cvh, 8);
                        __builtin_memcpy(&um, &cvm, 8);
                        const size_t eo = (size_t)(gc0 + bl) * Hdim + hq0;
                        __hip_atomic_store((u64*)&cwH[eo], uh,
                                           __ATOMIC_RELAXED, __HIP_MEMORY_SCOPE_AGENT);
                        __hip_atomic_store((u64*)&cwM[eo], um,
                                           __ATOMIC_RELAXED, __HIP_MEMORY_SCOPE_AGENT);
                    }
                    // drain own stores; 4th f-wave fires the producer flag
                    asm volatile("s_waitcnt vmcnt(0)" ::: "memory");
                    if (lane == 0) {
                        const unsigned old = __hip_atomic_fetch_add(&fdone, 1u,
                                             __ATOMIC_ACQ_REL, __HIP_MEMORY_SCOPE_WORKGROUP);
                        if (old == 4u * (unsigned)s + 3u)
                            __hip_atomic_store(&bar[g * 16 + rb], (unsigned)(s + 1),
                                               __ATOMIC_RELAXED, __HIP_MEMORY_SCOPE_AGENT);
                    }
                } else {
                    // last step: o-gate (full-K over resident tile), h = tanh(c)*o
                    f32x4 o0h = {0,0,0,0}, o0x = {0,0,0,0}, o1h = {0,0,0,0}, o1x = {0,0,0,0};
                    const int arow = blkh0 + sub * 16 + r;
                    #pragma unroll
                    for (int kk = 0; kk < NKK; ++kk) {
                        const float* wp = Woh + (size_t)arow * Hdim + kk * 32 + q * 8;
                        f16x8 who;
                        #pragma unroll
                        for (int jj = 0; jj < 8; ++jj) who[jj] = (_Float16)wp[jj];
                        const int lo = kk * 32 + q * 8;
                        const f16x8 bh0 = *(const f16x8*)&ldsH[ r       * CSTR + lo];
                        const f16x8 bm0 = *(const f16x8*)&ldsM[ r       * CSTR + lo];
                        const f16x8 bh1 = *(const f16x8*)&ldsH[(16 + r) * CSTR + lo];
                        const f16x8 bm1 = *(const f16x8*)&ldsM[(16 + r) * CSTR + lo];
                        o0h = mf(who, bh0, o0h);  o0x = mf(who, bm0, o0x);
                        o1h = mf(who, bh1, o1h);  o1x = mf(who, bm1, o1x);
                    }
                    #pragma unroll
                    for (int ct = 0; ct < 2; ++ct) {
                        const int bl = ct * 16 + r;
                        const int v  = xtok[bl * XSTR + s];
                        const float* tb = &tbl[(v * HB + sub * 16 + q * 4) * 4];
                        const f32x4 zh = ct ? a1h : a0h;
                        const f32x4 zx = ct ? a1x : a0x;
                        const f32x4 zoh = ct ? o1h : o0h;
                        const f32x4 zox = ct ? o1x : o0x;
                        f32x4 hv;
                        #pragma unroll
                        for (int reg = 0; reg < 4; ++reg) {
                            const float zf = zh[reg] + zx[reg] * SCL_INV;
                            const float zi = zp[(sub * 16 + q * 4 + reg) * GC + bl];
                            const float zo = zoh[reg] + zox[reg] * SCL_INV;
                            const float* tt = tb + reg * 4;
                            const float fg = sigf(zf + tt[0]);
                            const float ig = sigf(zi + tt[1]);
                            const float og = sigf(zo + tt[2]);
                            const float cn = tt[3] * ig + cst[ct][reg] * fg;
                            const float e  = __expf(-2.0f * fabsf(cn));
                            const float th = __builtin_copysignf((1.0f - e) / (1.0f + e), cn);
                            hv[reg] = th * og;
                        }
                        *(f32x4*)&hfin[(size_t)(gc0 + bl) * Hdim + hq0] = hv;
                    }
                }
            }
        }
    } else {
        // =================== staging waves (w = 8..11) =====================
        // 4 waves x 64 lanes = 256 slots; per chunk: 2 planes x 32 cols x 64 k
        // slot -> plane p, col, 16-k segment; 4 x 8B per lane per chunk.
        // Depth-2 pipeline: chunk j resident in dA, chunk j+1 prefetched to dB.
        const int sw   = w - 8;
        const int slot = sw * 64 + lane;      // 0..255
        const int p    = slot >> 7;           // plane 0=H 1=M
        const int colq = (slot >> 2) & 31;    // col
        const int seg  = slot & 3;            // 16-k segment
        _Float16* ldsP = p ? ldsM : ldsH;
        const size_t rowo = (size_t)(gc0 + colq) * Hdim;

        for (int s = 1; s < NSTEP; ++s) {
            const _Float16* cr = cbuf + (size_t)((s & 1) * 2 + p) * PLANE + rowo;
            const unsigned doneTgt = 8u * (unsigned)s;
            u64 dA[4], dB[4];
            while (__hip_atomic_load(&bar[g * 16 + 0], __ATOMIC_RELAXED,
                                     __HIP_MEMORY_SCOPE_AGENT) < (unsigned)s)
                __builtin_amdgcn_s_sleep(4);
            #pragma unroll
            for (int t = 0; t < 4; ++t)
                dA[t] = __hip_atomic_load((const u64*)&cr[(size_t)seg * 16 + 4 * t],
                                          __ATOMIC_RELAXED, __HIP_MEMORY_SCOPE_AGENT);
            for (int j = 0; j < NCH; ++j) {
                if (j + 1 < NCH) {
                    while (__hip_atomic_load(&bar[g * 16 + j + 1], __ATOMIC_RELAXED,
                                             __HIP_MEMORY_SCOPE_AGENT) < (unsigned)s)
                        __builtin_amdgcn_s_sleep(4);
                    const size_t ko = (size_t)(j + 1) * 64 + seg * 16;
                    #pragma unroll
                    for (int t = 0; t < 4; ++t)
                        dB[t] = __hip_atomic_load((const u64*)&cr[ko + 4 * t],
                                                  __ATOMIC_RELAXED, __HIP_MEMORY_SCOPE_AGENT);
                }
                while (__hip_atomic_load(&chunkDone[j], __ATOMIC_ACQUIRE,
                                         __HIP_MEMORY_SCOPE_WORKGROUP) < doneTgt)
                    __builtin_amdgcn_s_sleep(1);
                u64* dst = (u64*)&ldsP[colq * CSTR + j * 64 + seg * 16];
                dst[0] = dA[0]; dst[1] = dA[1]; dst[2] = dA[2]; dst[3] = dA[3];
                if (lane == 0)
                    __hip_atomic_fetch_add(&ldsRdy[j], 1u, __ATOMIC_RELEASE,
                                           __HIP_MEMORY_SCOPE_WORKGROUP);
                #pragma unroll
                for (int t = 0; t < 4; ++t) dA[t] = dB[t];
            }
        }
    }
}

__global__ void __launch_bounds__(64)
proj_kernel(const float* __restrict__ hfin, const float* __restrict__ Wph,
            const float* __restrict__ bpv, float* __restrict__ out)
{
    const int b = blockIdx.x;
    const int lane = threadIdx.x;
    float acc[NCls];
    #pragma unroll
    for (int c = 0; c < NCls; ++c) acc[c] = 0.f;
    const float* hb = &hfin[(size_t)b * Hdim];
    for (int i = 0; i < Hdim / 64; ++i) {
        const float hv = hb[lane + i * 64];
        #pragma unroll
        for (int c = 0; c < NCls; ++c)
            acc[c] += Wph[c * Hdim + lane + i * 64] * hv;
    }
    #pragma unroll
    for (int c = 0; c < NCls; ++c) {
        float v = acc[c];
        #pragma unroll
        for (int off = 32; off > 0; off >>= 1)
            v += __shfl_xor(v, off, 64);
        acc[c] = v + bpv[c];
    }
    float m = acc[0];
    #pragma unroll
    for (int c = 1; c < NCls; ++c) m = fmaxf(m, acc[c]);
    float ssum = 0.f;
    #pragma unroll
    for (int c = 0; c < NCls; ++c) ssum += __expf(acc[c] - m);
    const float lse = m + __logf(ssum);
    if (lane < NCls) out[b * NCls + lane] = acc[lane] - lse;
}

extern "C" void kernel_launch(void* const* d_in, const int* in_sizes, int n_in,
                              void* d_out, int out_size, void* d_ws, size_t ws_size,
                              hipStream_t stream)
{
    const int*   xk    = (const int*)d_in[0];
    const float* emb   = (const float*)d_in[1];
    const float* Wfx   = (const float*)d_in[2];
    const float* Wfh   = (const float*)d_in[3];
    const float* bfv   = (const float*)d_in[4];
    const float* Wix   = (const float*)d_in[5];
    const float* Wih   = (const float*)d_in[6];
    const float* biv   = (const float*)d_in[7];
    const float* Wox   = (const float*)d_in[8];
    const float* Woh   = (const float*)d_in[9];
    const float* bov   = (const float*)d_in[10];
    const float* Wcx   = (const float*)d_in[11];
    const float* bcv   = (const float*)d_in[12];
    const float* Wph   = (const float*)d_in[13];
    const float* bpv   = (const float*)d_in[14];
    const float* cinit = (const float*)d_in[15];

    char* ws = (char*)d_ws;
    _Float16*     cbuf = (_Float16*)(ws + WS_CBUF);
    float*        hfin = (float*)(ws + WS_HFIN);
    unsigned int* bar  = (unsigned int*)(ws + WS_BAR);
    _Float16*     wpk  = (_Float16*)(ws + WS_WPK);

    hipMemsetAsync(bar, 0, WS_BAR_BYTES, stream);

    prep_w<<<dim3(WP_FRAGS / 256), dim3(256), 0, stream>>>(Wfh, Wih, wpk);

    lstm_persist<<<dim3(NGRP * NRB), dim3(768), 0, stream>>>(
        xk, emb, Wfx, bfv, Wix, biv, Wox, Woh, bov, Wcx, bcv,
        cinit, wpk, cbuf, hfin, bar);

    proj_kernel<<<dim3(Bdim), dim3(64), 0, stream>>>(hfin, Wph, bpv, (float*)d_out);
}